// Round 5
// baseline (798.044 us; speedup 1.0000x reference)
//
#include <hip/hip_runtime.h>
#include <hip/hip_bf16.h>

typedef __hip_bfloat16 bf16;
typedef __attribute__((ext_vector_type(4))) float f32x4;
typedef __attribute__((ext_vector_type(8))) __bf16 bf16x8;

constexpr int kE   = 1152;
constexpr int kH   = 16;
constexpr int kHD2 = 36;
constexpr int kFF  = 4304;
constexpr int kFFP = 4352;   // padded to 34*128
constexpr int kB   = 32;
constexpr int kS   = 256;
constexpr int kT   = kB * kS;      // 8192 tokens
constexpr int kNQKV = 3 * kE;      // 3456
constexpr float kLambdaInit = 0.7778701f;   // 0.8 - 0.6*exp(-0.3*11)
constexpr float kRmsEps = 1e-6f;
constexpr float kSublnEps = 1e-5f;

__device__ inline void async_copy16(const void* gsrc, void* ldst) {
    __builtin_amdgcn_global_load_lds(
        (__attribute__((address_space(1))) void*)gsrc,
        (__attribute__((address_space(3))) void*)ldst, 16, 0, 0);
}

// ---------------- fused weight convert / pad (one launch) ----------------
constexpr int kNEE = kE * kE;                 // 1327104
constexpr int kW1N = kFFP * kE;               // 5013504
constexpr int kW2N = kE * kFFP;               // 5013504
constexpr long kCvtTotal = 4L * kNEE + kW1N + kW2N;   // 15335424

__global__ __launch_bounds__(256) void convert_all(
    const float* __restrict__ Wq, const float* __restrict__ Wk,
    const float* __restrict__ Wv, const float* __restrict__ Wo,
    const float* __restrict__ f1, const float* __restrict__ f2,
    bf16* __restrict__ wqkv, bf16* __restrict__ wo,
    bf16* __restrict__ w1, bf16* __restrict__ w2)
{
    long i = (long)blockIdx.x * 256 + threadIdx.x;
    if (i >= kCvtTotal) return;
    if (i < 3L * kNEE) {
        int j = (int)(i % kNEE);
        const float* src = (i < kNEE) ? Wq : (i < 2L * kNEE) ? Wk : Wv;
        wqkv[i] = __float2bfloat16(src[j]);
    } else if (i < 4L * kNEE) {
        int j = (int)(i - 3L * kNEE);
        wo[j] = __float2bfloat16(Wo[j]);
    } else if (i < 4L * kNEE + kW1N) {
        int j = (int)(i - 4L * kNEE);
        w1[j] = __float2bfloat16(j < kFF * kE ? f1[j] : 0.f);
    } else {
        int j = (int)(i - 4L * kNEE - kW1N);
        int n = j / kFFP, k = j - n * kFFP;
        w2[j] = __float2bfloat16(k < kFF ? f2[(long)n * kFF + k] : 0.f);
    }
}

__global__ __launch_bounds__(256) void prep_bias(
    const float* __restrict__ bq, const float* __restrict__ bk,
    const float* __restrict__ bv, const float* __restrict__ fb,
    float* __restrict__ bqkv, float* __restrict__ fbp)
{
    int i = blockIdx.x * 256 + threadIdx.x;
    if (i < kNQKV) {
        float v = (i < kE) ? bq[i] : (i < 2 * kE) ? bk[i - kE] : bv[i - 2 * kE];
        bqkv[i] = v;
    }
    if (i < kFFP) fbp[i] = (i < kFF) ? fb[i] : 0.f;
}

// ---------------- RMSNorm (fp32 in -> bf16 out) ----------------
__global__ __launch_bounds__(256) void rmsnorm_kernel(
    const float* __restrict__ x, const float* __restrict__ w,
    bf16* __restrict__ out, float eps)
{
    int row = blockIdx.x;
    const float* xr = x + (size_t)row * kE;
    float vals[5];
    float ss = 0.f;
    int n = 0;
    for (int j = threadIdx.x; j < kE; j += 256) {
        float v = xr[j];
        vals[n++] = v;
        ss += v * v;
    }
    for (int m = 32; m > 0; m >>= 1) ss += __shfl_xor(ss, m, 64);
    __shared__ float red[4];
    if ((threadIdx.x & 63) == 0) red[threadIdx.x >> 6] = ss;
    __syncthreads();
    float tot = red[0] + red[1] + red[2] + red[3];
    float scale = rsqrtf(tot / (float)kE + eps);
    n = 0;
    for (int j = threadIdx.x; j < kE; j += 256)
        out[(size_t)row * kE + j] = __float2bfloat16(vals[n++] * scale * w[j]);
}

// ---- bf16 NT GEMM, 128x128 tile, BK=64, double-buffered LDS ----
// A [M,K] bf16 row-major, Bw [N,K] bf16 row-major, C[M,N]. K % 64 == 0.
// K-loop: one barrier per iter; loads for tile k+1 issued right after the
// barrier, so they fly while tile k's MFMAs run (exposed latency ~= lat - compute).
// EPI: 0 = bf16 out (+bias), 1 = gelu bf16 out (+bias), 2 = fp32 out (+bias+add)
template <int EPI>
__global__ __launch_bounds__(256) void gemm_nt(
    const bf16* __restrict__ A, const bf16* __restrict__ Bw,
    const float* __restrict__ bias, const float* add, void* out,
    int N, int K)
{
    __shared__ __align__(16) bf16 lA[2][2][128 * 32];   // [buf][half][...]
    __shared__ __align__(16) bf16 lB[2][2][128 * 32];
    const int tid = threadIdx.x;
    const int lane = tid & 63;
    const int wave = tid >> 6;
    const int wm = wave >> 1, wn = wave & 1;
    const int bm = blockIdx.y, bn = blockIdx.x;
    const int quad = lane >> 4;
    const int l16 = lane & 15;

    const char* Ab = (const char*)(A + (size_t)bm * 128 * K);
    const char* Bb = (const char*)(Bw + (size_t)bn * 128 * K);
    const size_t rs = (size_t)K * 2;

    f32x4 acc[4][4] = {};

    const int lin0 = tid * 16;
    const int row0 = lin0 >> 6;
    const int kb0 = lin0 & 63;

    auto stage = [&](int d, int k0) {
#pragma unroll
        for (int h = 0; h < 2; ++h) {
            const size_t gk = (size_t)(k0 + h * 32) * 2;
#pragma unroll
            for (int it = 0; it < 2; ++it) {
                int lin = lin0 + it * 4096;
                int row = row0 + (it << 6);
                async_copy16(Ab + (size_t)row * rs + gk + kb0,
                             (char*)(&lA[d][h][0]) + lin);
            }
#pragma unroll
            for (int it = 0; it < 2; ++it) {
                int lin = lin0 + it * 4096;
                int row = row0 + (it << 6);
                async_copy16(Bb + (size_t)row * rs + gk + kb0,
                             (char*)(&lB[d][h][0]) + lin);
            }
        }
    };

    stage(0, 0);
    int cur = 0;
    for (int k0 = 0; k0 < K; k0 += 64) {
        __syncthreads();               // drains cur's loads; frees cur^1 for staging
        if (k0 + 64 < K) stage(cur ^ 1, k0 + 64);
#pragma unroll
        for (int h = 0; h < 2; ++h) {
            bf16x8 af[4], bfr[4];
#pragma unroll
            for (int mi = 0; mi < 4; ++mi)
                af[mi] = *(const bf16x8*)(&lA[cur][h][(wm * 64 + mi * 16 + l16) * 32 + quad * 8]);
#pragma unroll
            for (int ni = 0; ni < 4; ++ni)
                bfr[ni] = *(const bf16x8*)(&lB[cur][h][(wn * 64 + ni * 16 + l16) * 32 + quad * 8]);
#pragma unroll
            for (int mi = 0; mi < 4; ++mi)
#pragma unroll
                for (int ni = 0; ni < 4; ++ni)
                    acc[mi][ni] = __builtin_amdgcn_mfma_f32_16x16x32_bf16(
                        af[mi], bfr[ni], acc[mi][ni], 0, 0, 0);
        }
        cur ^= 1;
    }

    const int r0 = quad * 4;
    float bcol[4];
#pragma unroll
    for (int ni = 0; ni < 4; ++ni)
        bcol[ni] = bias[bn * 128 + wn * 64 + ni * 16 + l16];
#pragma unroll
    for (int mi = 0; mi < 4; ++mi) {
        int growb = bm * 128 + wm * 64 + mi * 16 + r0;
#pragma unroll
        for (int ni = 0; ni < 4; ++ni) {
            int gcol = bn * 128 + wn * 64 + ni * 16 + l16;
#pragma unroll
            for (int r = 0; r < 4; ++r) {
                size_t idx = (size_t)(growb + r) * N + gcol;
                float v = acc[mi][ni][r] + bcol[ni];
                if (EPI == 0) {
                    ((bf16*)out)[idx] = __float2bfloat16(v);
                } else if (EPI == 1) {
                    float u = 1.5957691216f * (v + 0.044715f * v * v * v);
                    float g = v / (1.f + __expf(-u));
                    ((bf16*)out)[idx] = __float2bfloat16(g);
                } else {
                    ((float*)out)[idx] = v + add[idx];
                }
            }
        }
    }
}

// ---------------- MFMA differential attention + subln ----------------
union U8 { bf16x8 v; uint4 u4; uint2 u2[2]; unsigned short e[8]; };

__global__ __launch_bounds__(256) void attn_mfma(
    const bf16* __restrict__ qkv,
    const float* __restrict__ lq1, const float* __restrict__ lk1,
    const float* __restrict__ lq2, const float* __restrict__ lk2,
    const float* __restrict__ subln_w, bf16* __restrict__ out)
{
    __shared__ __align__(16) bf16 Kp[256 * 136];   // 69632 B
    __shared__ __align__(16) bf16 VT[80 * 264];    // 42240 B
    __shared__ __align__(16) bf16 Pb[4 * 16 * 264];// 33792 B   (total 145664)

    const int tid = threadIdx.x;
    const int h = blockIdx.x & 15;
    const int b = blockIdx.x >> 4;
    const size_t tokbase = (size_t)b * kS;

    float s1 = 0.f, s2 = 0.f;
    for (int i = 0; i < kHD2; ++i) { s1 += lq1[i] * lk1[i]; s2 += lq2[i] * lk2[i]; }
    const float lam = __expf(s1) - __expf(s2) + kLambdaInit;

    for (int c = tid; c < 256 * 34; c += 256) {
        int row = c / 34, s4 = (c - row * 34) * 4;
        uint2 val = make_uint2(0u, 0u);
        const bf16* kg = qkv + (tokbase + row) * kNQKV + kE + h * 72;
        if (s4 < 36)                    val = *(const uint2*)(kg + s4);
        else if (s4 >= 64 && s4 < 100)  val = *(const uint2*)(kg + s4 - 28);
        *(uint2*)(Kp + row * 136 + s4) = val;
    }
    for (int c = tid; c < 256 * 18; c += 256) {
        int j = c / 18, s4 = (c - j * 18) * 4;
        union { uint2 u; unsigned short e[4]; } uu;
        uu.u = *(const uint2*)(qkv + (tokbase + j) * kNQKV + 2 * kE + h * 72 + s4);
#pragma unroll
        for (int x = 0; x < 4; ++x)
            ((unsigned short*)VT)[(s4 + x) * 264 + j] = uu.e[x];
    }
    for (int c = tid; c < 8 * 256; c += 256) {
        int d = 72 + (c >> 8), j = c & 255;
        ((unsigned short*)VT)[d * 264 + j] = 0;
    }
    __syncthreads();

    const int w = tid >> 6, lane = tid & 63, quad = lane >> 4, l16 = lane & 15;
    bf16* Pw = Pb + w * (16 * 264);
    const float sc = 0.117851130f;            // 1/sqrt(72)
    const float oscale = 1.f - kLambdaInit;

    float sw[5];
#pragma unroll
    for (int dt = 0; dt < 5; ++dt) {
        int d = dt * 16 + l16;
        sw[dt] = (d < 72) ? subln_w[d] : 0.f;
    }

    for (int s = 0; s < 4; ++s) {
        const int q0 = w * 64 + s * 16;
        const bf16* qg = qkv + (tokbase + q0 + l16) * kNQKV + h * 72;
        U8 qe0, qe1, qo0, qo1;
        qe0.u4 = *(const uint4*)(qg + quad * 8);
        qe1.u4 = *(const uint4*)(qg + 32);
        qo0.u2[0] = *(const uint2*)(qg + 36 + quad * 8);
        qo0.u2[1] = *(const uint2*)(qg + 40 + quad * 8);
        qo1.u2[0] = *(const uint2*)(qg + 68);
        qo1.u2[1] = *(const uint2*)(qg + 72);
#pragma unroll
        for (int j = 0; j < 8; ++j) {
            bool keep = (quad == 0) && (j < 4);
            if (!keep) { qe1.e[j] = 0; qo1.e[j] = 0; }
        }

        f32x4 se[16], so[16];
#pragma unroll
        for (int t = 0; t < 16; ++t) { se[t] = f32x4{0,0,0,0}; so[t] = f32x4{0,0,0,0}; }
#pragma unroll
        for (int t = 0; t < 16; ++t) {
            const bf16* kr = Kp + (t * 16 + l16) * 136;
            bf16x8 ke0 = *(const bf16x8*)(kr + quad * 8);
            bf16x8 ke1 = *(const bf16x8*)(kr + 32 + quad * 8);
            bf16x8 ko0 = *(const bf16x8*)(kr + 64 + quad * 8);
            bf16x8 ko1 = *(const bf16x8*)(kr + 96 + quad * 8);
            se[t] = __builtin_amdgcn_mfma_f32_16x16x32_bf16(qe0.v, ke0, se[t], 0, 0, 0);
            se[t] = __builtin_amdgcn_mfma_f32_16x16x32_bf16(qe1.v, ke1, se[t], 0, 0, 0);
            so[t] = __builtin_amdgcn_mfma_f32_16x16x32_bf16(qo0.v, ko0, so[t], 0, 0, 0);
            so[t] = __builtin_amdgcn_mfma_f32_16x16x32_bf16(qo1.v, ko1, so[t], 0, 0, 0);
        }

#pragma unroll
        for (int reg = 0; reg < 4; ++reg) {
            float me = -1e30f, mo = -1e30f;
#pragma unroll
            for (int t = 0; t < 16; ++t) {
                me = fmaxf(me, se[t][reg]);
                mo = fmaxf(mo, so[t][reg]);
            }
#pragma unroll
            for (int m = 1; m < 16; m <<= 1) {
                me = fmaxf(me, __shfl_xor(me, m, 64));
                mo = fmaxf(mo, __shfl_xor(mo, m, 64));
            }
            float sume = 0.f, sumo = 0.f;
#pragma unroll
            for (int t = 0; t < 16; ++t) {
                float pe = __expf((se[t][reg] - me) * sc);
                float po = __expf((so[t][reg] - mo) * sc);
                se[t][reg] = pe; sume += pe;
                so[t][reg] = po; sumo += po;
            }
#pragma unroll
            for (int m = 1; m < 16; m <<= 1) {
                sume += __shfl_xor(sume, m, 64);
                sumo += __shfl_xor(sumo, m, 64);
            }
            const float ie = 1.f / sume, io = lam / sumo;
            bf16* prow = Pw + (quad * 4 + reg) * 264;
#pragma unroll
            for (int t = 0; t < 16; ++t) {
                float p = se[t][reg] * ie - so[t][reg] * io;
                prow[t * 16 + l16] = __float2bfloat16(p);
            }
        }

        f32x4 oacc[5];
#pragma unroll
        for (int dt = 0; dt < 5; ++dt) oacc[dt] = f32x4{0,0,0,0};
#pragma unroll
        for (int k0 = 0; k0 < 256; k0 += 32) {
            bf16x8 pf = *(const bf16x8*)(Pw + l16 * 264 + k0 + quad * 8);
#pragma unroll
            for (int dt = 0; dt < 5; ++dt) {
                bf16x8 vf = *(const bf16x8*)(VT + (dt * 16 + l16) * 264 + k0 + quad * 8);
                oacc[dt] = __builtin_amdgcn_mfma_f32_16x16x32_bf16(pf, vf, oacc[dt], 0, 0, 0);
            }
        }

#pragma unroll
        for (int reg = 0; reg < 4; ++reg) {
            float ssq = 0.f;
#pragma unroll
            for (int dt = 0; dt < 5; ++dt) {
                float v = oacc[dt][reg];
                if (dt < 4 || l16 < 8) ssq += v * v;
            }
#pragma unroll
            for (int m = 1; m < 16; m <<= 1) ssq += __shfl_xor(ssq, m, 64);
            float scale = rsqrtf(ssq * (1.f / 72.f) + kSublnEps) * oscale;
            size_t orow = (tokbase + q0 + quad * 4 + reg) * (size_t)kE + h * 72;
#pragma unroll
            for (int dt = 0; dt < 5; ++dt) {
                int d = dt * 16 + l16;
                if (d < 72)
                    out[orow + d] = __float2bfloat16(oacc[dt][reg] * scale * sw[dt]);
            }
        }
    }
}

// ---------------- launch ----------------
extern "C" void kernel_launch(void* const* d_in, const int* in_sizes, int n_in,
                              void* d_out, int out_size, void* d_ws, size_t ws_size,
                              hipStream_t stream)
{
    const float* hidden = (const float*)d_in[0];
    const float* Wq = (const float*)d_in[1];
    const float* bq = (const float*)d_in[2];
    const float* Wk = (const float*)d_in[3];
    const float* bk = (const float*)d_in[4];
    const float* Wv = (const float*)d_in[5];
    const float* bv = (const float*)d_in[6];
    const float* Wo = (const float*)d_in[7];
    const float* bo = (const float*)d_in[8];
    const float* lq1 = (const float*)d_in[9];
    const float* lk1 = (const float*)d_in[10];
    const float* lq2 = (const float*)d_in[11];
    const float* lk2 = (const float*)d_in[12];
    const float* subln_w = (const float*)d_in[13];
    const float* rms1_w = (const float*)d_in[14];
    const float* rms2_w = (const float*)d_in[15];
    const float* fc1_w = (const float*)d_in[16];
    const float* fc1_b = (const float*)d_in[17];
    const float* fc2_w = (const float*)d_in[18];
    const float* fc2_b = (const float*)d_in[19];
    float* outp = (float*)d_out;

    char* wsp = (char*)d_ws;
    size_t off = 0;
    auto alloc = [&](size_t bytes) {
        char* p = wsp + off;
        off += (bytes + 255) & ~(size_t)255;
        return p;
    };
    bf16* wqkv = (bf16*)alloc((size_t)kNQKV * kE * 2);
    bf16* wo   = (bf16*)alloc((size_t)kE * kE * 2);
    bf16* w1   = (bf16*)alloc((size_t)kFFP * kE * 2);
    bf16* w2   = (bf16*)alloc((size_t)kE * kFFP * 2);
    float* bqkv = (float*)alloc((size_t)kNQKV * 4);
    float* b1   = (float*)alloc((size_t)kFFP * 4);
    bf16* xb    = (bf16*)alloc((size_t)kT * kE * 2);
    bf16* big   = (bf16*)alloc((size_t)kT * kFFP * 2);

    convert_all<<<(int)((kCvtTotal + 255) / 256), 256, 0, stream>>>(
        Wq, Wk, Wv, Wo, fc1_w, fc2_w, wqkv, wo, w1, w2);
    prep_bias<<<17, 256, 0, stream>>>(bq, bk, bv, fc1_b, bqkv, b1);

    rmsnorm_kernel<<<kT, 256, 0, stream>>>(hidden, rms1_w, xb, kRmsEps);
    gemm_nt<0><<<dim3(kNQKV / 128, kT / 128), 256, 0, stream>>>(
        xb, wqkv, bqkv, nullptr, big, kNQKV, kE);
    attn_mfma<<<kB * kH, 256, 0, stream>>>(
        big, lq1, lk1, lq2, lk2, subln_w, xb);
    // h = attn @ Wo^T + bo + hidden -> d_out (fp32)
    gemm_nt<2><<<dim3(kE / 128, kT / 128), 256, 0, stream>>>(
        xb, wo, bo, hidden, d_out, kE, kE);
    rmsnorm_kernel<<<kT, 256, 0, stream>>>(outp, rms2_w, xb, kRmsEps);
    gemm_nt<1><<<dim3(kFFP / 128, kT / 128), 256, 0, stream>>>(
        xb, w1, b1, nullptr, big, kFFP, kE);
    // out = act @ fc2^T + b2 + h
    gemm_nt<2><<<dim3(kE / 128, kT / 128), 256, 0, stream>>>(
        big, w2, fc2_b, outp, d_out, kE, kFFP);
}

// Round 6
// 748.937 us; speedup vs baseline: 1.0656x; 1.0656x over previous
//
#include <hip/hip_runtime.h>
#include <hip/hip_bf16.h>

typedef __hip_bfloat16 bf16;
typedef __attribute__((ext_vector_type(4))) float f32x4;
typedef __attribute__((ext_vector_type(8))) __bf16 bf16x8;

constexpr int kE   = 1152;
constexpr int kH   = 16;
constexpr int kHD2 = 36;
constexpr int kFF  = 4304;
constexpr int kFFP = 4352;   // padded to 34*128
constexpr int kB   = 32;
constexpr int kS   = 256;
constexpr int kT   = kB * kS;      // 8192 tokens
constexpr int kNQKV = 3 * kE;      // 3456
constexpr int kSplit = 4;          // fc2 split-K factor
constexpr int kKc   = kFFP / kSplit;   // 1088 per chunk
constexpr long kTE  = (long)kT * kE;   // 9437184
constexpr float kLambdaInit = 0.7778701f;   // 0.8 - 0.6*exp(-0.3*11)
constexpr float kRmsEps = 1e-6f;
constexpr float kSublnEps = 1e-5f;

__device__ inline void async_copy16(const void* gsrc, void* ldst) {
    __builtin_amdgcn_global_load_lds(
        (__attribute__((address_space(1))) void*)gsrc,
        (__attribute__((address_space(3))) void*)ldst, 16, 0, 0);
}

// ---------------- fused weight convert / pad, 4 elems/thread ----------------
constexpr int kNEE = kE * kE;                 // 1327104
constexpr int kW1N = kFFP * kE;               // 5013504
constexpr int kW2N = kE * kFFP;               // 5013504
constexpr long kCvtTotal = 4L * kNEE + kW1N + kW2N;   // 15335424 (all seg bounds %4==0)

__global__ __launch_bounds__(256) void convert_all(
    const float* __restrict__ Wq, const float* __restrict__ Wk,
    const float* __restrict__ Wv, const float* __restrict__ Wo,
    const float* __restrict__ f1, const float* __restrict__ f2,
    bf16* __restrict__ wqkv, bf16* __restrict__ wo,
    bf16* __restrict__ w1, bf16* __restrict__ w2)
{
    long i = ((long)blockIdx.x * 256 + threadIdx.x) * 4;
    if (i >= kCvtTotal) return;
    float4 v;
    bf16* dst;
    if (i < 3L * kNEE) {
        int j = (int)(i % kNEE);
        const float* src = (i < kNEE) ? Wq : (i < 2L * kNEE) ? Wk : Wv;
        v = *(const float4*)(src + j);
        dst = wqkv + i;
    } else if (i < 4L * kNEE) {
        int j = (int)(i - 3L * kNEE);
        v = *(const float4*)(Wo + j);
        dst = wo + j;
    } else if (i < 4L * kNEE + kW1N) {
        int j = (int)(i - 4L * kNEE);
        if (j < kFF * kE) v = *(const float4*)(f1 + j);
        else v = make_float4(0.f, 0.f, 0.f, 0.f);
        dst = w1 + j;
    } else {
        int j = (int)(i - 4L * kNEE - kW1N);
        int n = j / kFFP, k = j - n * kFFP;
        if (k < kFF) v = *(const float4*)(f2 + (long)n * kFF + k);
        else v = make_float4(0.f, 0.f, 0.f, 0.f);
        dst = w2 + j;
    }
    union { uint2 u; bf16 e[4]; } o;
    o.e[0] = __float2bfloat16(v.x); o.e[1] = __float2bfloat16(v.y);
    o.e[2] = __float2bfloat16(v.z); o.e[3] = __float2bfloat16(v.w);
    *(uint2*)dst = o.u;
}

__global__ __launch_bounds__(256) void prep_bias(
    const float* __restrict__ bq, const float* __restrict__ bk,
    const float* __restrict__ bv, const float* __restrict__ fb,
    float* __restrict__ bqkv, float* __restrict__ fbp)
{
    int i = blockIdx.x * 256 + threadIdx.x;
    if (i < kNQKV) {
        float v = (i < kE) ? bq[i] : (i < 2 * kE) ? bk[i - kE] : bv[i - 2 * kE];
        bqkv[i] = v;
    }
    if (i < kFFP) fbp[i] = (i < kFF) ? fb[i] : 0.f;
}

// ---------------- RMSNorm (fp32 in -> bf16 out) ----------------
__global__ __launch_bounds__(256) void rmsnorm_kernel(
    const float* __restrict__ x, const float* __restrict__ w,
    bf16* __restrict__ out, float eps)
{
    int row = blockIdx.x;
    const float* xr = x + (size_t)row * kE;
    float vals[5];
    float ss = 0.f;
    int n = 0;
    for (int j = threadIdx.x; j < kE; j += 256) {
        float v = xr[j];
        vals[n++] = v;
        ss += v * v;
    }
    for (int m = 32; m > 0; m >>= 1) ss += __shfl_xor(ss, m, 64);
    __shared__ float red[4];
    if ((threadIdx.x & 63) == 0) red[threadIdx.x >> 6] = ss;
    __syncthreads();
    float tot = red[0] + red[1] + red[2] + red[3];
    float scale = rsqrtf(tot / (float)kE + eps);
    n = 0;
    for (int j = threadIdx.x; j < kE; j += 256)
        out[(size_t)row * kE + j] = __float2bfloat16(vals[n++] * scale * w[j]);
}

// ---- bf16 NT GEMM, 128x128 tile, BK=64, single-buffer (R3 structure) ----
// A [M,ldk] bf16 row-major, Bw [N,ldk] bf16 row-major; loop over K (<= ldk).
// EPI: 0 bf16+bias | 1 gelu bf16+bias | 2 fp32+bias+add | 3 bf16 raw partial,
//      split chunk = blockIdx.z (A,B k-offset + out offset).
template <int EPI>
__global__ __launch_bounds__(256) void gemm_nt(
    const bf16* __restrict__ A, const bf16* __restrict__ Bw,
    const float* __restrict__ bias, const float* add, void* out,
    int N, int K, int ldk)
{
    __shared__ __align__(16) bf16 lA[2][128 * 32];
    __shared__ __align__(16) bf16 lB[2][128 * 32];
    const int tid = threadIdx.x;
    const int lane = tid & 63;
    const int wave = tid >> 6;
    const int wm = wave >> 1, wn = wave & 1;
    const int bm = blockIdx.y, bn = blockIdx.x;
    const int quad = lane >> 4;
    const int l16 = lane & 15;

    if (EPI == 3) {
        int s = blockIdx.z;
        A += (size_t)s * kKc;
        Bw += (size_t)s * kKc;
        out = (void*)((bf16*)out + (size_t)s * kTE);
    }

    const char* Ab = (const char*)(A + (size_t)bm * 128 * ldk);
    const char* Bb = (const char*)(Bw + (size_t)bn * 128 * ldk);
    const size_t rs = (size_t)ldk * 2;

    f32x4 acc[4][4] = {};

    const int lin0 = tid * 16;
    const int row0 = lin0 >> 6;
    const int kb0 = lin0 & 63;

    for (int k0 = 0; k0 < K; k0 += 64) {
#pragma unroll
        for (int h = 0; h < 2; ++h) {
            const size_t gk = (size_t)(k0 + h * 32) * 2;
#pragma unroll
            for (int it = 0; it < 2; ++it) {
                int lin = lin0 + it * 4096;
                int row = row0 + (it << 6);
                async_copy16(Ab + (size_t)row * rs + gk + kb0,
                             (char*)lA[h] + lin);
            }
#pragma unroll
            for (int it = 0; it < 2; ++it) {
                int lin = lin0 + it * 4096;
                int row = row0 + (it << 6);
                async_copy16(Bb + (size_t)row * rs + gk + kb0,
                             (char*)lB[h] + lin);
            }
        }
        __syncthreads();
#pragma unroll
        for (int h = 0; h < 2; ++h) {
            bf16x8 af[4], bfr[4];
#pragma unroll
            for (int mi = 0; mi < 4; ++mi)
                af[mi] = *(const bf16x8*)(lA[h] + (wm * 64 + mi * 16 + l16) * 32 + quad * 8);
#pragma unroll
            for (int ni = 0; ni < 4; ++ni)
                bfr[ni] = *(const bf16x8*)(lB[h] + (wn * 64 + ni * 16 + l16) * 32 + quad * 8);
#pragma unroll
            for (int mi = 0; mi < 4; ++mi)
#pragma unroll
                for (int ni = 0; ni < 4; ++ni)
                    acc[mi][ni] = __builtin_amdgcn_mfma_f32_16x16x32_bf16(
                        af[mi], bfr[ni], acc[mi][ni], 0, 0, 0);
        }
        __syncthreads();
    }

    const int r0 = quad * 4;
    float bcol[4];
#pragma unroll
    for (int ni = 0; ni < 4; ++ni)
        bcol[ni] = (EPI == 3) ? 0.f : bias[bn * 128 + wn * 64 + ni * 16 + l16];
#pragma unroll
    for (int mi = 0; mi < 4; ++mi) {
        int growb = bm * 128 + wm * 64 + mi * 16 + r0;
#pragma unroll
        for (int ni = 0; ni < 4; ++ni) {
            int gcol = bn * 128 + wn * 64 + ni * 16 + l16;
#pragma unroll
            for (int r = 0; r < 4; ++r) {
                size_t idx = (size_t)(growb + r) * N + gcol;
                float v = acc[mi][ni][r] + bcol[ni];
                if (EPI == 0) {
                    ((bf16*)out)[idx] = __float2bfloat16(v);
                } else if (EPI == 1) {
                    float u = 1.5957691216f * (v + 0.044715f * v * v * v);
                    float g = v / (1.f + __expf(-u));
                    ((bf16*)out)[idx] = __float2bfloat16(g);
                } else if (EPI == 2) {
                    ((float*)out)[idx] = v + add[idx];
                } else {
                    ((bf16*)out)[idx] = __float2bfloat16(v);
                }
            }
        }
    }
}

// ---- fc2 split-K reduce: io (holds h) += sum of 4 bf16 partials + bias ----
__global__ __launch_bounds__(256) void fc2_reduce(
    const bf16* __restrict__ p, const float* __restrict__ b2,
    float* __restrict__ io)
{
    long base = ((long)blockIdx.x * 256 + threadIdx.x) * 4;
    if (base >= kTE) return;
    float4 h = *(float4*)(io + base);
    int col = (int)(base % kE);
    float s0 = 0.f, s1 = 0.f, s2 = 0.f, s3 = 0.f;
#pragma unroll
    for (int s = 0; s < kSplit; ++s) {
        union { uint2 u; bf16 e[4]; } v;
        v.u = *(const uint2*)(p + s * kTE + base);
        s0 += __bfloat162float(v.e[0]); s1 += __bfloat162float(v.e[1]);
        s2 += __bfloat162float(v.e[2]); s3 += __bfloat162float(v.e[3]);
    }
    float4 r;
    r.x = h.x + s0 + b2[col];
    r.y = h.y + s1 + b2[col + 1];
    r.z = h.z + s2 + b2[col + 2];
    r.w = h.w + s3 + b2[col + 3];
    *(float4*)(io + base) = r;
}

// ---------------- MFMA differential attention + subln ----------------
union U8 { bf16x8 v; uint4 u4; uint2 u2[2]; unsigned short e[8]; };

__global__ __launch_bounds__(256) void attn_mfma(
    const bf16* __restrict__ qkv,
    const float* __restrict__ lq1, const float* __restrict__ lk1,
    const float* __restrict__ lq2, const float* __restrict__ lk2,
    const float* __restrict__ subln_w, bf16* __restrict__ out)
{
    __shared__ __align__(16) bf16 Kp[256 * 136];   // 69632 B
    __shared__ __align__(16) bf16 VT[80 * 264];    // 42240 B
    __shared__ __align__(16) bf16 Pb[4 * 16 * 264];// 33792 B   (total 145664)

    const int tid = threadIdx.x;
    const int h = blockIdx.x & 15;
    const int b = blockIdx.x >> 4;
    const size_t tokbase = (size_t)b * kS;

    float s1 = 0.f, s2 = 0.f;
    for (int i = 0; i < kHD2; ++i) { s1 += lq1[i] * lk1[i]; s2 += lq2[i] * lk2[i]; }
    const float lam = __expf(s1) - __expf(s2) + kLambdaInit;

    for (int c = tid; c < 256 * 34; c += 256) {
        int row = c / 34, s4 = (c - row * 34) * 4;
        uint2 val = make_uint2(0u, 0u);
        const bf16* kg = qkv + (tokbase + row) * kNQKV + kE + h * 72;
        if (s4 < 36)                    val = *(const uint2*)(kg + s4);
        else if (s4 >= 64 && s4 < 100)  val = *(const uint2*)(kg + s4 - 28);
        *(uint2*)(Kp + row * 136 + s4) = val;
    }
    for (int c = tid; c < 256 * 18; c += 256) {
        int j = c / 18, s4 = (c - j * 18) * 4;
        union { uint2 u; unsigned short e[4]; } uu;
        uu.u = *(const uint2*)(qkv + (tokbase + j) * kNQKV + 2 * kE + h * 72 + s4);
#pragma unroll
        for (int x = 0; x < 4; ++x)
            ((unsigned short*)VT)[(s4 + x) * 264 + j] = uu.e[x];
    }
    for (int c = tid; c < 8 * 256; c += 256) {
        int d = 72 + (c >> 8), j = c & 255;
        ((unsigned short*)VT)[d * 264 + j] = 0;
    }
    __syncthreads();

    const int w = tid >> 6, lane = tid & 63, quad = lane >> 4, l16 = lane & 15;
    bf16* Pw = Pb + w * (16 * 264);
    const float sc = 0.117851130f;            // 1/sqrt(72)
    const float oscale = 1.f - kLambdaInit;

    float sw[5];
#pragma unroll
    for (int dt = 0; dt < 5; ++dt) {
        int d = dt * 16 + l16;
        sw[dt] = (d < 72) ? subln_w[d] : 0.f;
    }

    for (int s = 0; s < 4; ++s) {
        const int q0 = w * 64 + s * 16;
        const bf16* qg = qkv + (tokbase + q0 + l16) * kNQKV + h * 72;
        U8 qe0, qe1, qo0, qo1;
        qe0.u4 = *(const uint4*)(qg + quad * 8);
        qe1.u4 = *(const uint4*)(qg + 32);
        qo0.u2[0] = *(const uint2*)(qg + 36 + quad * 8);
        qo0.u2[1] = *(const uint2*)(qg + 40 + quad * 8);
        qo1.u2[0] = *(const uint2*)(qg + 68);
        qo1.u2[1] = *(const uint2*)(qg + 72);
#pragma unroll
        for (int j = 0; j < 8; ++j) {
            bool keep = (quad == 0) && (j < 4);
            if (!keep) { qe1.e[j] = 0; qo1.e[j] = 0; }
        }

        f32x4 se[16], so[16];
#pragma unroll
        for (int t = 0; t < 16; ++t) { se[t] = f32x4{0,0,0,0}; so[t] = f32x4{0,0,0,0}; }
#pragma unroll
        for (int t = 0; t < 16; ++t) {
            const bf16* kr = Kp + (t * 16 + l16) * 136;
            bf16x8 ke0 = *(const bf16x8*)(kr + quad * 8);
            bf16x8 ke1 = *(const bf16x8*)(kr + 32 + quad * 8);
            bf16x8 ko0 = *(const bf16x8*)(kr + 64 + quad * 8);
            bf16x8 ko1 = *(const bf16x8*)(kr + 96 + quad * 8);
            se[t] = __builtin_amdgcn_mfma_f32_16x16x32_bf16(qe0.v, ke0, se[t], 0, 0, 0);
            se[t] = __builtin_amdgcn_mfma_f32_16x16x32_bf16(qe1.v, ke1, se[t], 0, 0, 0);
            so[t] = __builtin_amdgcn_mfma_f32_16x16x32_bf16(qo0.v, ko0, so[t], 0, 0, 0);
            so[t] = __builtin_amdgcn_mfma_f32_16x16x32_bf16(qo1.v, ko1, so[t], 0, 0, 0);
        }

#pragma unroll
        for (int reg = 0; reg < 4; ++reg) {
            float me = -1e30f, mo = -1e30f;
#pragma unroll
            for (int t = 0; t < 16; ++t) {
                me = fmaxf(me, se[t][reg]);
                mo = fmaxf(mo, so[t][reg]);
            }
#pragma unroll
            for (int m = 1; m < 16; m <<= 1) {
                me = fmaxf(me, __shfl_xor(me, m, 64));
                mo = fmaxf(mo, __shfl_xor(mo, m, 64));
            }
            float sume = 0.f, sumo = 0.f;
#pragma unroll
            for (int t = 0; t < 16; ++t) {
                float pe = __expf((se[t][reg] - me) * sc);
                float po = __expf((so[t][reg] - mo) * sc);
                se[t][reg] = pe; sume += pe;
                so[t][reg] = po; sumo += po;
            }
#pragma unroll
            for (int m = 1; m < 16; m <<= 1) {
                sume += __shfl_xor(sume, m, 64);
                sumo += __shfl_xor(sumo, m, 64);
            }
            const float ie = 1.f / sume, io = lam / sumo;
            bf16* prow = Pw + (quad * 4 + reg) * 264;
#pragma unroll
            for (int t = 0; t < 16; ++t) {
                float p = se[t][reg] * ie - so[t][reg] * io;
                prow[t * 16 + l16] = __float2bfloat16(p);
            }
        }

        f32x4 oacc[5];
#pragma unroll
        for (int dt = 0; dt < 5; ++dt) oacc[dt] = f32x4{0,0,0,0};
#pragma unroll
        for (int k0 = 0; k0 < 256; k0 += 32) {
            bf16x8 pf = *(const bf16x8*)(Pw + l16 * 264 + k0 + quad * 8);
#pragma unroll
            for (int dt = 0; dt < 5; ++dt) {
                bf16x8 vf = *(const bf16x8*)(VT + (dt * 16 + l16) * 264 + k0 + quad * 8);
                oacc[dt] = __builtin_amdgcn_mfma_f32_16x16x32_bf16(pf, vf, oacc[dt], 0, 0, 0);
            }
        }

#pragma unroll
        for (int reg = 0; reg < 4; ++reg) {
            float ssq = 0.f;
#pragma unroll
            for (int dt = 0; dt < 5; ++dt) {
                float v = oacc[dt][reg];
                if (dt < 4 || l16 < 8) ssq += v * v;
            }
#pragma unroll
            for (int m = 1; m < 16; m <<= 1) ssq += __shfl_xor(ssq, m, 64);
            float scale = rsqrtf(ssq * (1.f / 72.f) + kSublnEps) * oscale;
            size_t orow = (tokbase + q0 + quad * 4 + reg) * (size_t)kE + h * 72;
#pragma unroll
            for (int dt = 0; dt < 5; ++dt) {
                int d = dt * 16 + l16;
                if (d < 72)
                    out[orow + d] = __float2bfloat16(oacc[dt][reg] * scale * sw[dt]);
            }
        }
    }
}

// ---------------- launch ----------------
extern "C" void kernel_launch(void* const* d_in, const int* in_sizes, int n_in,
                              void* d_out, int out_size, void* d_ws, size_t ws_size,
                              hipStream_t stream)
{
    const float* hidden = (const float*)d_in[0];
    const float* Wq = (const float*)d_in[1];
    const float* bq = (const float*)d_in[2];
    const float* Wk = (const float*)d_in[3];
    const float* bk = (const float*)d_in[4];
    const float* Wv = (const float*)d_in[5];
    const float* bv = (const float*)d_in[6];
    const float* Wo = (const float*)d_in[7];
    const float* bo = (const float*)d_in[8];
    const float* lq1 = (const float*)d_in[9];
    const float* lk1 = (const float*)d_in[10];
    const float* lq2 = (const float*)d_in[11];
    const float* lk2 = (const float*)d_in[12];
    const float* subln_w = (const float*)d_in[13];
    const float* rms1_w = (const float*)d_in[14];
    const float* rms2_w = (const float*)d_in[15];
    const float* fc1_w = (const float*)d_in[16];
    const float* fc1_b = (const float*)d_in[17];
    const float* fc2_w = (const float*)d_in[18];
    const float* fc2_b = (const float*)d_in[19];
    float* outp = (float*)d_out;

    char* wsp = (char*)d_ws;
    size_t off = 0;
    auto alloc = [&](size_t bytes) {
        char* p = wsp + off;
        off += (bytes + 255) & ~(size_t)255;
        return p;
    };
    bf16* wqkv = (bf16*)alloc((size_t)kNQKV * kE * 2);
    bf16* wo   = (bf16*)alloc((size_t)kE * kE * 2);
    bf16* w1   = (bf16*)alloc((size_t)kFFP * kE * 2);
    bf16* w2   = (bf16*)alloc((size_t)kE * kFFP * 2);
    float* bqkv = (float*)alloc((size_t)kNQKV * 4);
    float* b1   = (float*)alloc((size_t)kFFP * 4);
    bf16* xb    = (bf16*)alloc((size_t)kT * kE * 2);
    bf16* big   = (bf16*)alloc((size_t)kT * kFFP * 2);
    bf16* part  = (bf16*)alloc((size_t)kSplit * kTE * 2);   // fc2 split-K partials
    const bool splitk = (off <= ws_size);

    convert_all<<<(int)((kCvtTotal / 4 + 255) / 256), 256, 0, stream>>>(
        Wq, Wk, Wv, Wo, fc1_w, fc2_w, wqkv, wo, w1, w2);
    prep_bias<<<17, 256, 0, stream>>>(bq, bk, bv, fc1_b, bqkv, b1);

    rmsnorm_kernel<<<kT, 256, 0, stream>>>(hidden, rms1_w, xb, kRmsEps);
    gemm_nt<0><<<dim3(kNQKV / 128, kT / 128), 256, 0, stream>>>(
        xb, wqkv, bqkv, nullptr, big, kNQKV, kE, kE);
    attn_mfma<<<kB * kH, 256, 0, stream>>>(
        big, lq1, lk1, lq2, lk2, subln_w, xb);
    // h = attn @ Wo^T + bo + hidden -> d_out (fp32)
    gemm_nt<2><<<dim3(kE / 128, kT / 128), 256, 0, stream>>>(
        xb, wo, bo, hidden, d_out, kE, kE, kE);
    rmsnorm_kernel<<<kT, 256, 0, stream>>>(outp, rms2_w, xb, kRmsEps);
    gemm_nt<1><<<dim3(kFFP / 128, kT / 128), 256, 0, stream>>>(
        xb, w1, b1, nullptr, big, kFFP, kE, kE);
    if (splitk) {
        // fc2 split-K: 4 chunks of K=1088, bf16 partials, then fused reduce
        gemm_nt<3><<<dim3(kE / 128, kT / 128, kSplit), 256, 0, stream>>>(
            big, w2, nullptr, nullptr, part, kE, kKc, kFFP);
        fc2_reduce<<<(int)(kTE / 4 / 256), 256, 0, stream>>>(part, fc2_b, outp);
    } else {
        gemm_nt<2><<<dim3(kE / 128, kT / 128), 256, 0, stream>>>(
            big, w2, fc2_b, outp, d_out, kE, kFFP, kFFP);
    }
}